// Round 1
// baseline (15723.997 us; speedup 1.0000x reference)
//
#include <hip/hip_runtime.h>
#include <stdint.h>

typedef unsigned short u16;
typedef __attribute__((ext_vector_type(8))) short bf16x8;
typedef __attribute__((ext_vector_type(4))) float f32x4;

#define T_STEPS 512
#define BATCH   64
#define HID     1024
#define NWG_SCAN 128

__device__ __forceinline__ u16 f2bf(float f) {
  union { float f; uint32_t u; } v; v.f = f;
  uint32_t r = (v.u + 0x7fffu + ((v.u >> 16) & 1u)) >> 16;  // RNE
  return (u16)r;
}
__device__ __forceinline__ float bf2f(u16 h) {
  union { uint32_t u; float f; } v; v.u = ((uint32_t)h) << 16;
  return v.f;
}
__device__ __forceinline__ float sigmoidf_(float x) {
  return 1.0f / (1.0f + __expf(-x));
}

// ---------------------------------------------------------------------------
// Transpose + cast: dst[n][k] = bf16(src[k][n]), 1024x1024
// ---------------------------------------------------------------------------
__global__ __launch_bounds__(256) void transpose_cast(const float* __restrict__ src,
                                                      u16* __restrict__ dst) {
  __shared__ float tile[32][33];
  int bx = blockIdx.x * 32;  // k block (src row)
  int by = blockIdx.y * 32;  // n block (src col)
  for (int i = threadIdx.y; i < 32; i += 8)
    tile[i][threadIdx.x] = src[(size_t)(bx + i) * 1024 + by + threadIdx.x];
  __syncthreads();
  for (int i = threadIdx.y; i < 32; i += 8)
    dst[(size_t)(by + i) * 1024 + bx + threadIdx.x] = f2bf(tile[threadIdx.x][i]);
}

// bias3 = concat(b_r, b_u, b_h)
__global__ void concat_bias(const float* __restrict__ br, const float* __restrict__ bu,
                            const float* __restrict__ bh, float* __restrict__ b3) {
  int i = blockIdx.x * blockDim.x + threadIdx.x;  // 0..3071
  float v = (i < 1024) ? br[i] : (i < 2048 ? bu[i - 1024] : bh[i - 2048]);
  b3[i] = v;
}

// ---------------------------------------------------------------------------
// GEMM: C[M,N] = A[M,K] @ B[K,N] + bias, with B given TRANSPOSED (BT[N][K]).
// A is fp32 (cast on the fly) or bf16. Output fp32 or bf16.
// 128x128 tile, BK=32, 256 thr (4 waves, 2x2 of 64x64), mfma 16x16x32 bf16.
// LDS chunks (16B) XOR-swizzled: slot s = bb ^ (m&3) ^ ((m>>2)&3)  -> 2-way banks.
// ---------------------------------------------------------------------------
template <int A_F32, int OUT_BF16>
__global__ __launch_bounds__(256) void gemm_bt(const void* __restrict__ Av,
                                               const u16* __restrict__ BT,
                                               const float* __restrict__ bias,
                                               void* __restrict__ Cv,
                                               int M, int N, int K) {
  __shared__ u16 Asm[4096];  // [m 0..127][slot 0..3][8]  (8KB)
  __shared__ u16 Bsm[4096];
  const int tid = threadIdx.x;
  const int lane = tid & 63;
  const int wv = tid >> 6;
  const int wm = wv >> 1, wn = wv & 1;
  const int m0 = blockIdx.x * 128;
  const int n0 = blockIdx.y * 128;

  f32x4 acc[4][4];
#pragma unroll
  for (int i = 0; i < 4; i++)
#pragma unroll
    for (int j = 0; j < 4; j++) acc[i][j] = (f32x4){0.f, 0.f, 0.f, 0.f};

  for (int kt = 0; kt < K; kt += 32) {
    __syncthreads();
#pragma unroll
    for (int i = 0; i < 2; i++) {
      int q = tid + i * 256;          // chunk store index 0..511
      int m = q >> 2, s = q & 3;      // row within tile, stored slot
      int bb = s ^ ((m & 3) ^ ((m >> 2) & 3));  // which k-chunk of 8
      if (A_F32) {
        const float* srcp = (const float*)Av + (size_t)(m0 + m) * K + kt + bb * 8;
        bf16x8 o;
#pragma unroll
        for (int e = 0; e < 8; e++) o[e] = (short)f2bf(srcp[e]);
        *(bf16x8*)&Asm[q * 8] = o;
      } else {
        const u16* srcp = (const u16*)Av + (size_t)(m0 + m) * K + kt + bb * 8;
        *(bf16x8*)&Asm[q * 8] = *(const bf16x8*)srcp;
      }
      const u16* srcb = BT + (size_t)(n0 + m) * K + kt + bb * 8;
      *(bf16x8*)&Bsm[q * 8] = *(const bf16x8*)srcb;
    }
    __syncthreads();

    bf16x8 af[4], bfr[4];
    int bb = lane >> 4;
#pragma unroll
    for (int mt = 0; mt < 4; mt++) {
      int m = wm * 64 + mt * 16 + (lane & 15);
      int s = bb ^ ((m & 3) ^ ((m >> 2) & 3));
      af[mt] = *(const bf16x8*)&Asm[m * 32 + s * 8];
    }
#pragma unroll
    for (int nt = 0; nt < 4; nt++) {
      int n = wn * 64 + nt * 16 + (lane & 15);
      int s = bb ^ ((n & 3) ^ ((n >> 2) & 3));
      bfr[nt] = *(const bf16x8*)&Bsm[n * 32 + s * 8];
    }
#pragma unroll
    for (int mt = 0; mt < 4; mt++)
#pragma unroll
      for (int nt = 0; nt < 4; nt++)
        acc[mt][nt] = __builtin_amdgcn_mfma_f32_16x16x32_bf16(af[mt], bfr[nt], acc[mt][nt], 0, 0, 0);
  }

  // epilogue: D row = quad*4+reg, col = lane&15
#pragma unroll
  for (int nt = 0; nt < 4; nt++) {
    int col = n0 + wn * 64 + nt * 16 + (lane & 15);
    float bv = bias[col];
#pragma unroll
    for (int mt = 0; mt < 4; mt++) {
#pragma unroll
      for (int r = 0; r < 4; r++) {
        int row = m0 + wm * 64 + mt * 16 + (lane >> 4) * 4 + r;
        float v = acc[mt][nt][r] + bv;
        if (OUT_BF16)
          ((u16*)Cv)[(size_t)row * N + col] = f2bf(v);
        else
          ((float*)Cv)[(size_t)row * N + col] = v;
      }
    }
  }
}

// ---------------------------------------------------------------------------
// Grid barrier: monotonic counter, agent-scope fences for cross-XCD visibility.
// All NWG_SCAN blocks are co-resident (128 WGs, 64KB LDS -> <=2/CU on 256 CUs).
// ---------------------------------------------------------------------------
__device__ __forceinline__ void grid_barrier(unsigned* bar, unsigned& phase) {
  __syncthreads();  // drains vmcnt: all block stores at least in L2
  phase++;
  if (threadIdx.x == 0) {
    __builtin_amdgcn_fence(__ATOMIC_RELEASE, "agent");  // wb L2 -> LLC
    __hip_atomic_fetch_add(bar, 1u, __ATOMIC_RELAXED, __HIP_MEMORY_SCOPE_AGENT);
    unsigned target = phase * (unsigned)NWG_SCAN;
    while (__hip_atomic_load(bar, __ATOMIC_RELAXED, __HIP_MEMORY_SCOPE_AGENT) < target) {
      __builtin_amdgcn_s_sleep(1);
    }
    __builtin_amdgcn_fence(__ATOMIC_ACQUIRE, "agent");  // inv L1/L2
  }
  __syncthreads();
}

// ---------------------------------------------------------------------------
// Persistent GRU scan. 128 WGs x 256 thr.
// LDS: pass1 weight slice (16 cols of [W_hr|W_hu], all K) 32KB at lds[0]
//      pass2 weight slice (16 cols of W_hh, all K)        32KB at lds[16384]
// Layout per slice: [kb 0..31][nl 0..15][slot 0..3][8 shorts], slot XOR-swizzled.
// Per step: pass1 (4 waves: rt=wave, ct=wg) computes R,U for cols wg*16..+16 of
// 2048; writes A2=bf16(R*s_prev) and Ubuf. Barrier. pass2 (waves 0,1; task id
// 2*wg+wv) computes Hc and state update. Barrier.
// ---------------------------------------------------------------------------
__global__ __launch_bounds__(256) void gru_scan(const float* __restrict__ W_hr,
                                                const float* __restrict__ W_hu,
                                                const float* __restrict__ W_hh,
                                                const u16* __restrict__ Xproj,  // [T*B][3072] bf16
                                                u16* __restrict__ SB,           // [T+1][B][H] bf16
                                                float* __restrict__ Ubuf,       // [B][H]
                                                u16* __restrict__ A2,           // [B][H] bf16
                                                float* __restrict__ out_states, // [T*B][H] fp32
                                                unsigned* __restrict__ bar) {
  __shared__ u16 lds[32768];  // 64KB
  const int tid = threadIdx.x;
  const int lane = tid & 63;
  const int wv = tid >> 6;
  const int wg = blockIdx.x;  // 0..127

  // ---- one-time LDS weight fill ----
  {
    const float* Wsrc = (wg < 64) ? W_hr : W_hu;
    const int cbase1 = (wg & 63) * 16;
    for (int idx = tid; idx < 16384; idx += 256) {
      int kin = idx & 31, nl = (idx >> 5) & 15, kb = idx >> 9;
      float v = Wsrc[(size_t)(kb * 32 + kin) * 1024 + cbase1 + nl];
      int slot = (kin >> 3) ^ (nl & 3) ^ ((nl >> 2) & 3);
      lds[((kb * 16 + nl) * 4 + slot) * 8 + (kin & 7)] = f2bf(v);
    }
    const int cbase2 = (wg >> 1) * 16;
    for (int idx = tid; idx < 16384; idx += 256) {
      int kin = idx & 31, nl = (idx >> 5) & 15, kb = idx >> 9;
      float v = W_hh[(size_t)(kb * 32 + kin) * 1024 + cbase2 + nl];
      int slot = (kin >> 3) ^ (nl & 3) ^ ((nl >> 2) & 3);
      lds[16384 + ((kb * 16 + nl) * 4 + slot) * 8 + (kin & 7)] = f2bf(v);
    }
  }
  __syncthreads();

  unsigned phase = 0;
  const int bb = lane >> 4;
  const int nl = lane & 15;
  const int slot = bb ^ ((nl & 3) ^ ((nl >> 2) & 3));

  for (int t = 0; t < T_STEPS; t++) {
    const u16* SBt = SB + (size_t)t * BATCH * HID;

    // ---- pass1: R and U (cols c = wg*16 + nl of 2048), rows rt=wv ----
    {
      const int rt = wv;
      f32x4 acc = (f32x4){0.f, 0.f, 0.f, 0.f};
      const u16* abase = SBt + (size_t)(rt * 16 + nl) * HID + bb * 8;
      const u16* lb = &lds[(nl * 4 + slot) * 8];
#pragma unroll 8
      for (int kb = 0; kb < 32; kb++) {
        bf16x8 a = *(const bf16x8*)(abase + kb * 32);
        bf16x8 b = *(const bf16x8*)(lb + kb * 512);
        acc = __builtin_amdgcn_mfma_f32_16x16x32_bf16(a, b, acc, 0, 0, 0);
      }
      const int c = wg * 16 + nl;   // 0..2047
      const int g = c >> 10;        // 0 = r, 1 = u
      const int j = c & 1023;
#pragma unroll
      for (int r = 0; r < 4; r++) {
        int b_ = rt * 16 + (lane >> 4) * 4 + r;
        float xr = bf2f(Xproj[(size_t)(t * 64 + b_) * 3072 + g * 1024 + j]);
        float gate = sigmoidf_(acc[r] + xr);
        if (g == 0) {
          float sprev = bf2f(SBt[(size_t)b_ * HID + j]);
          A2[(size_t)b_ * HID + j] = f2bf(gate * sprev);
        } else {
          Ubuf[(size_t)b_ * HID + j] = gate;
        }
      }
    }
    grid_barrier(bar, phase);

    // ---- pass2: Hc + state update (cols ct*16 + nl of 1024) ----
    if (wv < 2) {
      const int id = 2 * wg + wv;
      const int ct = id >> 2, rt = id & 3;
      f32x4 acc = (f32x4){0.f, 0.f, 0.f, 0.f};
      const u16* abase = A2 + (size_t)(rt * 16 + nl) * HID + bb * 8;
      const u16* lb = &lds[16384 + (nl * 4 + slot) * 8];
#pragma unroll 8
      for (int kb = 0; kb < 32; kb++) {
        bf16x8 a = *(const bf16x8*)(abase + kb * 32);
        bf16x8 b = *(const bf16x8*)(lb + kb * 512);
        acc = __builtin_amdgcn_mfma_f32_16x16x32_bf16(a, b, acc, 0, 0, 0);
      }
      const int j = ct * 16 + nl;
#pragma unroll
      for (int r = 0; r < 4; r++) {
        int b_ = rt * 16 + (lane >> 4) * 4 + r;
        float xh = bf2f(Xproj[(size_t)(t * 64 + b_) * 3072 + 2048 + j]);
        float hc = tanhf(acc[r] + xh);
        float U = Ubuf[(size_t)b_ * HID + j];
        float sprev = bf2f(SBt[(size_t)b_ * HID + j]);
        float snew = U * sprev + (1.f - U) * hc;
        out_states[(size_t)(t * 64 + b_) * HID + j] = snew;
        SB[(size_t)(t + 1) * BATCH * HID + (size_t)b_ * HID + j] = f2bf(snew);
      }
    }
    grid_barrier(bar, phase);
  }
}

// ---------------------------------------------------------------------------
extern "C" void kernel_launch(void* const* d_in, const int* in_sizes, int n_in,
                              void* d_out, int out_size, void* d_ws, size_t ws_size,
                              hipStream_t stream) {
  const float* X    = (const float*)d_in[0];
  const float* W_xr = (const float*)d_in[1];
  const float* W_xu = (const float*)d_in[2];
  const float* W_xh = (const float*)d_in[3];
  const float* W_hr = (const float*)d_in[4];
  const float* W_hu = (const float*)d_in[5];
  const float* W_hh = (const float*)d_in[6];
  const float* b_r  = (const float*)d_in[7];
  const float* b_u  = (const float*)d_in[8];
  const float* b_h  = (const float*)d_in[9];
  const float* W_hq = (const float*)d_in[10];
  const float* b_q  = (const float*)d_in[11];

  char* ws = (char*)d_ws;
  size_t off = 0;
  auto alloc = [&](size_t bytes) {
    char* p = ws + off;
    off = (off + bytes + 255) & ~(size_t)255;
    return p;
  };
  u16*      WxT   = (u16*)alloc(3072ull * 1024 * 2);        // B^T for phase1
  u16*      WhqT  = (u16*)alloc(1024ull * 1024 * 2);        // B^T for phase3
  float*    bias3 = (float*)alloc(3072ull * 4);
  u16*      Xproj = (u16*)alloc(32768ull * 3072 * 2);       // [T*B][3H] bf16
  u16*      SB    = (u16*)alloc(513ull * BATCH * HID * 2);  // [T+1][B][H] bf16
  u16*      A2    = (u16*)alloc((size_t)BATCH * HID * 2);
  float*    Ubuf  = (float*)alloc((size_t)BATCH * HID * 4);
  unsigned* bar   = (unsigned*)alloc(256);

  hipMemsetAsync(SB, 0, (size_t)BATCH * HID * 2, stream);  // state_0 = 0
  hipMemsetAsync(bar, 0, 4, stream);

  dim3 tb(32, 8);
  dim3 tg(32, 32);
  transpose_cast<<<tg, tb, 0, stream>>>(W_xr, WxT);
  transpose_cast<<<tg, tb, 0, stream>>>(W_xu, WxT + 1024ull * 1024);
  transpose_cast<<<tg, tb, 0, stream>>>(W_xh, WxT + 2048ull * 1024);
  transpose_cast<<<tg, tb, 0, stream>>>(W_hq, WhqT);
  concat_bias<<<12, 256, 0, stream>>>(b_r, b_u, b_h, bias3);

  // Phase 1: Xproj = X @ [W_xr|W_xu|W_xh] + bias3   (bf16 out)
  gemm_bt<1, 1><<<dim3(256, 24), 256, 0, stream>>>(X, WxT, bias3, Xproj, 32768, 3072, 1024);

  // Phase 2: recurrent scan (persistent, grid barrier)
  float* out_states = (float*)d_out + 33554432ull;  // after outputs [T*B*O]
  gru_scan<<<NWG_SCAN, 256, 0, stream>>>(W_hr, W_hu, W_hh, Xproj, SB, Ubuf, A2, out_states, bar);

  // Phase 3: outputs = states @ W_hq + b_q   (fp32 out to d_out[0:T*B*O])
  gemm_bt<0, 0><<<dim3(256, 8), 256, 0, stream>>>(SB + (size_t)BATCH * HID, WhqT, b_q,
                                                  d_out, 32768, 1024, 1024);
}

// Round 2
// 11080.753 us; speedup vs baseline: 1.4190x; 1.4190x over previous
//
#include <hip/hip_runtime.h>
#include <stdint.h>

typedef unsigned short u16;
typedef __attribute__((ext_vector_type(8))) short bf16x8;
typedef __attribute__((ext_vector_type(4))) float f32x4;

#define T_STEPS 512
#define BATCH   64
#define HID     1024
#define NWG_SCAN 128

__device__ __forceinline__ u16 f2bf(float f) {
  union { float f; uint32_t u; } v; v.f = f;
  uint32_t r = (v.u + 0x7fffu + ((v.u >> 16) & 1u)) >> 16;  // RNE
  return (u16)r;
}
__device__ __forceinline__ float bf2f(u16 h) {
  union { uint32_t u; float f; } v; v.u = ((uint32_t)h) << 16;
  return v.f;
}
__device__ __forceinline__ float sigmoidf_(float x) {
  return 1.0f / (1.0f + __expf(-x));
}

// write-through store (sc1): visible at LLC once vmcnt acks -> no buffer_wbl2
// needed at the grid barrier. Local XCD L2 stays coherent with its own store.
__device__ __forceinline__ void store_bf16_sc1(u16* p, u16 v) {
  uint32_t vv = v;
  asm volatile("global_store_short %0, %1, off sc1" :: "v"(p), "v"(vv) : "memory");
}

// ---------------------------------------------------------------------------
// Transpose + cast: dst[n][k] = bf16(src[k][n]), 1024x1024
// ---------------------------------------------------------------------------
__global__ __launch_bounds__(256) void transpose_cast(const float* __restrict__ src,
                                                      u16* __restrict__ dst) {
  __shared__ float tile[32][33];
  int bx = blockIdx.x * 32;  // k block (src row)
  int by = blockIdx.y * 32;  // n block (src col)
  for (int i = threadIdx.y; i < 32; i += 8)
    tile[i][threadIdx.x] = src[(size_t)(bx + i) * 1024 + by + threadIdx.x];
  __syncthreads();
  for (int i = threadIdx.y; i < 32; i += 8)
    dst[(size_t)(by + i) * 1024 + bx + threadIdx.x] = f2bf(tile[threadIdx.x][i]);
}

// bias3 = concat(b_r, b_u, b_h)
__global__ void concat_bias(const float* __restrict__ br, const float* __restrict__ bu,
                            const float* __restrict__ bh, float* __restrict__ b3) {
  int i = blockIdx.x * blockDim.x + threadIdx.x;  // 0..3071
  float v = (i < 1024) ? br[i] : (i < 2048 ? bu[i - 1024] : bh[i - 2048]);
  b3[i] = v;
}

// ---------------------------------------------------------------------------
// GEMM: C[M,N] = A[M,K] @ B[K,N] + bias, B given transposed (BT[N][K]).
// 128x128 tile, BK=32, 256 thr, mfma 16x16x32 bf16, XOR-swizzled LDS.
// ---------------------------------------------------------------------------
template <int A_F32, int OUT_BF16>
__global__ __launch_bounds__(256) void gemm_bt(const void* __restrict__ Av,
                                               const u16* __restrict__ BT,
                                               const float* __restrict__ bias,
                                               void* __restrict__ Cv,
                                               int M, int N, int K) {
  __shared__ u16 Asm[4096];
  __shared__ u16 Bsm[4096];
  const int tid = threadIdx.x;
  const int lane = tid & 63;
  const int wv = tid >> 6;
  const int wm = wv >> 1, wn = wv & 1;
  const int m0 = blockIdx.x * 128;
  const int n0 = blockIdx.y * 128;

  f32x4 acc[4][4];
#pragma unroll
  for (int i = 0; i < 4; i++)
#pragma unroll
    for (int j = 0; j < 4; j++) acc[i][j] = (f32x4){0.f, 0.f, 0.f, 0.f};

  for (int kt = 0; kt < K; kt += 32) {
    __syncthreads();
#pragma unroll
    for (int i = 0; i < 2; i++) {
      int q = tid + i * 256;
      int m = q >> 2, s = q & 3;
      int bb = s ^ ((m & 3) ^ ((m >> 2) & 3));
      if (A_F32) {
        const float* srcp = (const float*)Av + (size_t)(m0 + m) * K + kt + bb * 8;
        bf16x8 o;
#pragma unroll
        for (int e = 0; e < 8; e++) o[e] = (short)f2bf(srcp[e]);
        *(bf16x8*)&Asm[q * 8] = o;
      } else {
        const u16* srcp = (const u16*)Av + (size_t)(m0 + m) * K + kt + bb * 8;
        *(bf16x8*)&Asm[q * 8] = *(const bf16x8*)srcp;
      }
      const u16* srcb = BT + (size_t)(n0 + m) * K + kt + bb * 8;
      *(bf16x8*)&Bsm[q * 8] = *(const bf16x8*)srcb;
    }
    __syncthreads();

    bf16x8 af[4], bfr[4];
    int bb = lane >> 4;
#pragma unroll
    for (int mt = 0; mt < 4; mt++) {
      int m = wm * 64 + mt * 16 + (lane & 15);
      int s = bb ^ ((m & 3) ^ ((m >> 2) & 3));
      af[mt] = *(const bf16x8*)&Asm[m * 32 + s * 8];
    }
#pragma unroll
    for (int nt = 0; nt < 4; nt++) {
      int n = wn * 64 + nt * 16 + (lane & 15);
      int s = bb ^ ((n & 3) ^ ((n >> 2) & 3));
      bfr[nt] = *(const bf16x8*)&Bsm[n * 32 + s * 8];
    }
#pragma unroll
    for (int mt = 0; mt < 4; mt++)
#pragma unroll
      for (int nt = 0; nt < 4; nt++)
        acc[mt][nt] = __builtin_amdgcn_mfma_f32_16x16x32_bf16(af[mt], bfr[nt], acc[mt][nt], 0, 0, 0);
  }

#pragma unroll
  for (int nt = 0; nt < 4; nt++) {
    int col = n0 + wn * 64 + nt * 16 + (lane & 15);
    float bv = bias[col];
#pragma unroll
    for (int mt = 0; mt < 4; mt++) {
#pragma unroll
      for (int r = 0; r < 4; r++) {
        int row = m0 + wm * 64 + mt * 16 + (lane >> 4) * 4 + r;
        float v = acc[mt][nt][r] + bv;
        if (OUT_BF16)
          ((u16*)Cv)[(size_t)row * N + col] = f2bf(v);
        else
          ((float*)Cv)[(size_t)row * N + col] = v;
      }
    }
  }
}

// ---------------------------------------------------------------------------
// Grid barrier WITHOUT cache-maintenance fences. All cross-WG data is written
// with sc1 (write-through) stores to addresses never previously cached by a
// consumer XCD, so visibility needs only: vmcnt(0) drain (the compiler emits
// it before s_barrier; we add an explicit one for safety) + counter at LLC.
// ---------------------------------------------------------------------------
__device__ __forceinline__ void grid_barrier(unsigned* bar, unsigned& phase) {
  asm volatile("s_waitcnt vmcnt(0)" ::: "memory");
  __syncthreads();
  phase++;
  if (threadIdx.x == 0) {
    __hip_atomic_fetch_add(bar, 1u, __ATOMIC_RELAXED, __HIP_MEMORY_SCOPE_AGENT);
    unsigned target = phase * (unsigned)NWG_SCAN;
    while (__hip_atomic_load(bar, __ATOMIC_RELAXED, __HIP_MEMORY_SCOPE_AGENT) < target) {
      __builtin_amdgcn_s_sleep(1);
    }
  }
  __syncthreads();
}

// ---------------------------------------------------------------------------
// Persistent GRU scan. 128 WGs x 256 thr.
// WG w<64 : pass1 r-gate, cols w*16..+16.   Writes A2 = bf16(R*s_prev) with
//           sc1 stores, OVERLAYED onto Xproj's r-region for step t (dead data,
//           rotating addresses -> no stale-L2 reads possible).
// WG w>=64: pass1 u-gate, cols (w-64)*16..+16. Keeps U and s_prev in REGISTERS.
//           pass2 (all 4 waves: rt=wave, ct=w-64): Hc GEMM over A2-overlay,
//           state update using register-carried U/s_prev; SB[t+1] via sc1.
// LDS: 32KB pass1 weight slice + 32KB W_hh slice (w>=64 only).
// ---------------------------------------------------------------------------
__global__ __launch_bounds__(256) void gru_scan(const float* __restrict__ W_hr,
                                                const float* __restrict__ W_hu,
                                                const float* __restrict__ W_hh,
                                                u16* __restrict__ Xproj,        // [T*B][3072] bf16 (r-region mutated)
                                                u16* __restrict__ SB,           // [T+1][B][H] bf16
                                                float* __restrict__ out_states, // [T*B][H] fp32
                                                unsigned* __restrict__ bar) {
  __shared__ u16 lds[32768];  // 64KB
  const int tid = threadIdx.x;
  const int lane = tid & 63;
  const int wv = tid >> 6;
  const int wg = blockIdx.x;  // 0..127

  // ---- one-time LDS weight fill ----
  {
    const float* Wsrc = (wg < 64) ? W_hr : W_hu;
    const int cbase1 = (wg & 63) * 16;
    for (int idx = tid; idx < 16384; idx += 256) {
      int kin = idx & 31, nl = (idx >> 5) & 15, kb = idx >> 9;
      float v = Wsrc[(size_t)(kb * 32 + kin) * 1024 + cbase1 + nl];
      int slot = (kin >> 3) ^ (nl & 3) ^ ((nl >> 2) & 3);
      lds[((kb * 16 + nl) * 4 + slot) * 8 + (kin & 7)] = f2bf(v);
    }
    if (wg >= 64) {
      const int cbase2 = (wg - 64) * 16;
      for (int idx = tid; idx < 16384; idx += 256) {
        int kin = idx & 31, nl = (idx >> 5) & 15, kb = idx >> 9;
        float v = W_hh[(size_t)(kb * 32 + kin) * 1024 + cbase2 + nl];
        int slot = (kin >> 3) ^ (nl & 3) ^ ((nl >> 2) & 3);
        lds[16384 + ((kb * 16 + nl) * 4 + slot) * 8 + (kin & 7)] = f2bf(v);
      }
    }
  }
  __syncthreads();

  unsigned phase = 0;
  const int bb = lane >> 4;
  const int nl = lane & 15;
  const int quad = lane >> 4;
  const int slot = bb ^ ((nl & 3) ^ ((nl >> 2) & 3));

  float Ureg[4], Sreg[4];  // register-carried across barrier (wg>=64)

  for (int t = 0; t < T_STEPS; t++) {
    const u16* SBt = SB + (size_t)t * BATCH * HID;
    u16* A2 = Xproj + (size_t)t * 64 * 3072;  // r-region overlay, row stride 3072

    // ---- pass1: gate GEMM (rows rt=wv, cols wg*16+nl of 2048) ----
    {
      const int rt = wv;
      // prefetch all 32 A-fragments (state rows, normal cached loads)
      const u16* abase = SBt + (size_t)(rt * 16 + nl) * HID + bb * 8;
      bf16x8 af[32];
#pragma unroll
      for (int kb = 0; kb < 32; kb++) af[kb] = *(const bf16x8*)(abase + kb * 32);

      f32x4 acc = (f32x4){0.f, 0.f, 0.f, 0.f};
      const u16* lb = &lds[(nl * 4 + slot) * 8];
#pragma unroll
      for (int kb = 0; kb < 32; kb++) {
        bf16x8 b = *(const bf16x8*)(lb + kb * 512);
        acc = __builtin_amdgcn_mfma_f32_16x16x32_bf16(af[kb], b, acc, 0, 0, 0);
      }

      if (wg < 64) {
        const int j = wg * 16 + nl;
#pragma unroll
        for (int r = 0; r < 4; r++) {
          int b_ = rt * 16 + quad * 4 + r;
          u16* xaddr = A2 + (size_t)b_ * 3072 + j;
          float xr = bf2f(*xaddr);
          float gate = sigmoidf_(acc[r] + xr);
          float sprev = bf2f(SBt[(size_t)b_ * HID + j]);
          store_bf16_sc1(xaddr, f2bf(gate * sprev));  // A2 overlay, write-through
        }
      } else {
        const int j = (wg - 64) * 16 + nl;
#pragma unroll
        for (int r = 0; r < 4; r++) {
          int b_ = rt * 16 + quad * 4 + r;
          float xu = bf2f(Xproj[(size_t)(t * 64 + b_) * 3072 + 1024 + j]);
          Ureg[r] = sigmoidf_(acc[r] + xu);
          Sreg[r] = bf2f(SBt[(size_t)b_ * HID + j]);
        }
      }
    }
    grid_barrier(bar, phase);

    // ---- pass2: Hc GEMM + state update (wg>=64; rt=wv, ct=wg-64) ----
    if (wg >= 64) {
      const int rt = wv;
      const int ct = wg - 64;
      const u16* abase = A2 + (size_t)(rt * 16 + nl) * 3072 + bb * 8;  // overlay, stride 3072
      bf16x8 af[32];
#pragma unroll
      for (int kb = 0; kb < 32; kb++) af[kb] = *(const bf16x8*)(abase + kb * 32);

      f32x4 acc = (f32x4){0.f, 0.f, 0.f, 0.f};
      const u16* lb = &lds[16384 + (nl * 4 + slot) * 8];
#pragma unroll
      for (int kb = 0; kb < 32; kb++) {
        bf16x8 b = *(const bf16x8*)(lb + kb * 512);
        acc = __builtin_amdgcn_mfma_f32_16x16x32_bf16(af[kb], b, acc, 0, 0, 0);
      }

      const int j = ct * 16 + nl;
#pragma unroll
      for (int r = 0; r < 4; r++) {
        int b_ = rt * 16 + quad * 4 + r;
        float xh = bf2f(Xproj[(size_t)(t * 64 + b_) * 3072 + 2048 + j]);
        float hc = tanhf(acc[r] + xh);
        float snew = Ureg[r] * Sreg[r] + (1.f - Ureg[r]) * hc;
        out_states[(size_t)(t * 64 + b_) * HID + j] = snew;                 // normal store (d_out)
        store_bf16_sc1(SB + (size_t)(t + 1) * BATCH * HID + (size_t)b_ * HID + j,
                       f2bf(snew));                                         // write-through
      }
    }
    grid_barrier(bar, phase);
  }
}

// ---------------------------------------------------------------------------
extern "C" void kernel_launch(void* const* d_in, const int* in_sizes, int n_in,
                              void* d_out, int out_size, void* d_ws, size_t ws_size,
                              hipStream_t stream) {
  const float* X    = (const float*)d_in[0];
  const float* W_xr = (const float*)d_in[1];
  const float* W_xu = (const float*)d_in[2];
  const float* W_xh = (const float*)d_in[3];
  const float* W_hr = (const float*)d_in[4];
  const float* W_hu = (const float*)d_in[5];
  const float* W_hh = (const float*)d_in[6];
  const float* b_r  = (const float*)d_in[7];
  const float* b_u  = (const float*)d_in[8];
  const float* b_h  = (const float*)d_in[9];
  const float* W_hq = (const float*)d_in[10];
  const float* b_q  = (const float*)d_in[11];

  char* ws = (char*)d_ws;
  size_t off = 0;
  auto alloc = [&](size_t bytes) {
    char* p = ws + off;
    off = (off + bytes + 255) & ~(size_t)255;
    return p;
  };
  u16*      WxT   = (u16*)alloc(3072ull * 1024 * 2);        // B^T for phase1
  u16*      WhqT  = (u16*)alloc(1024ull * 1024 * 2);        // B^T for phase3
  float*    bias3 = (float*)alloc(3072ull * 4);
  u16*      Xproj = (u16*)alloc(32768ull * 3072 * 2);       // [T*B][3H] bf16
  u16*      SB    = (u16*)alloc(513ull * BATCH * HID * 2);  // [T+1][B][H] bf16
  unsigned* bar   = (unsigned*)alloc(256);

  hipMemsetAsync(SB, 0, (size_t)BATCH * HID * 2, stream);  // state_0 = 0
  hipMemsetAsync(bar, 0, 4, stream);

  dim3 tb(32, 8);
  dim3 tg(32, 32);
  transpose_cast<<<tg, tb, 0, stream>>>(W_xr, WxT);
  transpose_cast<<<tg, tb, 0, stream>>>(W_xu, WxT + 1024ull * 1024);
  transpose_cast<<<tg, tb, 0, stream>>>(W_xh, WxT + 2048ull * 1024);
  transpose_cast<<<tg, tb, 0, stream>>>(W_hq, WhqT);
  concat_bias<<<12, 256, 0, stream>>>(b_r, b_u, b_h, bias3);

  // Phase 1: Xproj = X @ [W_xr|W_xu|W_xh] + bias3   (bf16 out)
  gemm_bt<1, 1><<<dim3(256, 24), 256, 0, stream>>>(X, WxT, bias3, Xproj, 32768, 3072, 1024);

  // Phase 2: recurrent scan (persistent, fence-free grid barrier)
  float* out_states = (float*)d_out + 33554432ull;  // after outputs [T*B*O]
  gru_scan<<<NWG_SCAN, 256, 0, stream>>>(W_hr, W_hu, W_hh, Xproj, SB, out_states, bar);

  // Phase 3: outputs = states @ W_hq + b_q   (fp32 out to d_out[0:T*B*O])
  gemm_bt<0, 0><<<dim3(256, 8), 256, 0, stream>>>(SB + (size_t)BATCH * HID, WhqT, b_q,
                                                  d_out, 32768, 1024, 1024);
}